// Round 9
// baseline (2672.272 us; speedup 1.0000x reference)
//
#include <hip/hip_runtime.h>
#include <hip/hip_bf16.h>
#include <stdint.h>

// Problem constants (fixed by setup_inputs): B=4, S=1024, E=1024, H=16, D=64
// Dtypes (r0-r8 bisects): ALL inputs fp32 (mask int32). OUTPUTS fp32
// (reference returns jnp.float32; harness doc: "else float*").
#define BATCH 4
#define SEQ   1024
#define EMB   1024
#define NH    16
#define HD    64

__device__ __forceinline__ float bf2f(uint32_t u16) {
    union { uint32_t u; float f; } c; c.u = u16 << 16; return c.f;
}
__device__ __forceinline__ uint16_t f2bf(float f) {
    __hip_bfloat16 h = __float2bfloat16(f);
    return *reinterpret_cast<uint16_t*>(&h);
}

// C[M=4096, N=1024] = X[M,K=1024] @ W[N,K]^T + bias[N]. Scalar-VALU, fp32 math.
// XF32: X fp32 (q/k/v inputs); else X bf16 (ctx in ws). W/bias fp32.
// scatter==1: bf16 store to [B,H,S,D] ws buffer.
// scatter==0: FP32 store, row-major [M][N] (final output).
template<bool XF32>
__global__ __launch_bounds__(256) void proj_scalar(
        const void* __restrict__ Xv, const float* __restrict__ W,
        const float* __restrict__ bias, void* __restrict__ outv, int scatter)
{
    __shared__ float Xs[32][68];   // [kk][m]
    __shared__ float Ws[32][68];   // [kk][n]

    const int tid = threadIdx.x;
    const int tx = tid & 15;       // n-dir
    const int ty = tid >> 4;       // m-dir
    const int m0 = blockIdx.y * 64;
    const int n0 = blockIdx.x * 64;

    const float*    Xf = (const float*)Xv;
    const uint16_t* Xb = (const uint16_t*)Xv;

    const int r = tid >> 2;        // 0..63 staging row
    const int c = (tid & 3) * 8;   // k base 0,8,16,24

    float acc[4][4];
    #pragma unroll
    for (int i = 0; i < 4; ++i)
        #pragma unroll
        for (int j = 0; j < 4; ++j) acc[i][j] = 0.f;

    for (int k0 = 0; k0 < EMB; k0 += 32) {
        if (XF32) {
            const float* p = Xf + (size_t)(m0 + r) * EMB + k0 + c;
            #pragma unroll
            for (int i = 0; i < 8; ++i) Xs[c + i][r] = p[i];
        } else {
            const uint16_t* p = Xb + (size_t)(m0 + r) * EMB + k0 + c;
            #pragma unroll
            for (int i = 0; i < 8; ++i) Xs[c + i][r] = bf2f(p[i]);
        }
        {
            const float* p = W + (size_t)(n0 + r) * EMB + k0 + c;
            #pragma unroll
            for (int i = 0; i < 8; ++i) Ws[c + i][r] = p[i];
        }
        __syncthreads();

        #pragma unroll
        for (int kk = 0; kk < 32; ++kk) {
            float4 a = *(const float4*)(&Xs[kk][ty * 4]);
            float4 b = *(const float4*)(&Ws[kk][tx * 4]);
            acc[0][0] += a.x * b.x; acc[0][1] += a.x * b.y; acc[0][2] += a.x * b.z; acc[0][3] += a.x * b.w;
            acc[1][0] += a.y * b.x; acc[1][1] += a.y * b.y; acc[1][2] += a.y * b.z; acc[1][3] += a.y * b.w;
            acc[2][0] += a.z * b.x; acc[2][1] += a.z * b.y; acc[2][2] += a.z * b.z; acc[2][3] += a.z * b.w;
            acc[3][0] += a.w * b.x; acc[3][1] += a.w * b.y; acc[3][2] += a.w * b.z; acc[3][3] += a.w * b.w;
        }
        __syncthreads();
    }

    #pragma unroll
    for (int i = 0; i < 4; ++i) {
        const int m = m0 + ty * 4 + i;
        #pragma unroll
        for (int j = 0; j < 4; ++j) {
            const int n = n0 + tx * 4 + j;
            const float v = acc[i][j] + bias[n];
            if (scatter) {
                // [B,H,S,D]: b=m>>10, s=m&1023, h=n>>6, d=n&63  (bf16 ws)
                size_t idx = (size_t)(((m >> 10) * NH + (n >> 6)) * SEQ + (m & 1023)) * HD + (n & 63);
                ((uint16_t*)outv)[idx] = f2bf(v);
            } else {
                ((float*)outv)[(size_t)m * EMB + n] = v;   // fp32 final out
            }
        }
    }
}

// Boring, correct-by-construction attention (r5-audited). One block = one
// (row, b), 256 threads, loops over the 16 heads. Thread t owns
// k = t + 256*j, j=0..3. LDS tree reductions for softmax.
// ctx: bf16 ws buffer. attn_out: FP32 final output.
__global__ __launch_bounds__(256) void attn_boring(
        const uint16_t* __restrict__ Qb, const uint16_t* __restrict__ Kb,
        const uint16_t* __restrict__ Vb, const int* __restrict__ mask,
        uint16_t* __restrict__ ctx, float* __restrict__ attn_out)
{
    __shared__ float qrow[64];
    __shared__ float sc[1024];
    __shared__ float red[256];
    __shared__ float part[4][64];

    const int row = blockIdx.x;    // 0..1023
    const int b   = blockIdx.y;    // 0..3
    const int t   = threadIdx.x;   // 0..255

    const int* mrow = mask + ((size_t)b * SEQ + row) * SEQ;
    int mk[4];
    #pragma unroll
    for (int j = 0; j < 4; ++j) mk[j] = (mrow[t + 256 * j] != 0);

    float attn_acc[4] = {0.f, 0.f, 0.f, 0.f};

    const int g = t >> 6;          // 0..3 (k-quarter for ctx phase)
    const int d = t & 63;          // 0..63

    for (int h = 0; h < NH; ++h) {
        const size_t hb = ((size_t)(b * NH + h)) * SEQ * HD;

        if (t < 64) qrow[t] = bf2f(Qb[hb + (size_t)row * HD + t]);
        __syncthreads();

        float e[4];
        float mx = -3.0e38f;
        #pragma unroll
        for (int j = 0; j < 4; ++j) {
            const int k = t + 256 * j;
            const uint16_t* kp = Kb + hb + (size_t)k * HD;
            float acc = 0.f;
            for (int dd = 0; dd < 64; ++dd) acc += qrow[dd] * bf2f(kp[dd]);
            acc = mk[j] ? acc * 0.125f : -1.0e9f;
            e[j] = acc;
            mx = fmaxf(mx, acc);
        }

        red[t] = mx;
        __syncthreads();
        for (int off = 128; off > 0; off >>= 1) {
            if (t < off) red[t] = fmaxf(red[t], red[t + off]);
            __syncthreads();
        }
        mx = red[0];
        __syncthreads();

        float l = 0.f;
        #pragma unroll
        for (int j = 0; j < 4; ++j) { e[j] = __expf(e[j] - mx); l += e[j]; }
        red[t] = l;
        __syncthreads();
        for (int off = 128; off > 0; off >>= 1) {
            if (t < off) red[t] = red[t] + red[t + off];
            __syncthreads();
        }
        l = red[0];
        __syncthreads();

        const float inv = 1.0f / l;
        #pragma unroll
        for (int j = 0; j < 4; ++j) {
            const float p = e[j] * inv;
            sc[t + 256 * j] = p;
            attn_acc[j] += p * 0.0625f;   // mean over 16 heads
        }
        __syncthreads();

        float ca = 0.f;
        const int kb = g * 256;
        for (int k = kb; k < kb + 256; ++k)
            ca += sc[k] * bf2f(Vb[hb + (size_t)k * HD + d]);
        part[g][d] = ca;
        __syncthreads();
        if (t < 64) {
            const float v = part[0][t] + part[1][t] + part[2][t] + part[3][t];
            ctx[((size_t)(b * SEQ + row) * NH + h) * HD + t] = f2bf(v);
        }
        __syncthreads();
    }

    float* ap = attn_out + ((size_t)b * SEQ + row) * SEQ;
    #pragma unroll
    for (int j = 0; j < 4; ++j) ap[t + 256 * j] = attn_acc[j];
}

extern "C" void kernel_launch(void* const* d_in, const int* in_sizes, int n_in,
                              void* d_out, int out_size, void* d_ws, size_t ws_size,
                              hipStream_t stream) {
    // ALL inputs fp32 (mask int32) — proven by r7/r8 NaN bisects.
    const float* q_in = (const float*)d_in[0];
    const float* k_in = (const float*)d_in[1];
    const float* v_in = (const float*)d_in[2];
    const int*   mask = (const int*)d_in[3];
    const float* Wq = (const float*)d_in[4];
    const float* bq = (const float*)d_in[5];
    const float* Wk = (const float*)d_in[6];
    const float* bk = (const float*)d_in[7];
    const float* Wv = (const float*)d_in[8];
    const float* bv = (const float*)d_in[9];
    const float* Wo = (const float*)d_in[10];
    const float* bo = (const float*)d_in[11];

    float* out      = (float*)d_out;                         // [B,S,E] fp32
    float* attn_out = out + (size_t)BATCH * SEQ * EMB;       // [B,S,S] fp32

    const size_t qkv_elems = (size_t)BATCH * NH * SEQ * HD;  // 4 Mi elements

    // ws >= 32 MB proven by r3/r4 == r5 bit-identity. Q,K,V,ctx all bf16 in ws.
    uint16_t* Qb  = (uint16_t*)d_ws;
    uint16_t* Kb  = Qb + qkv_elems;
    uint16_t* Vb  = Kb + qkv_elems;
    uint16_t* ctx = Vb + qkv_elems;                          // [B,S,E] bf16

    dim3 ggrid(EMB / 64, (BATCH * SEQ) / 64);                // 16 x 64
    proj_scalar<true><<<ggrid, 256, 0, stream>>>(q_in, Wq, bq, Qb, 1);
    proj_scalar<true><<<ggrid, 256, 0, stream>>>(k_in, Wk, bk, Kb, 1);
    proj_scalar<true><<<ggrid, 256, 0, stream>>>(v_in, Wv, bv, Vb, 1);

    attn_boring<<<dim3(SEQ, BATCH), 256, 0, stream>>>(Qb, Kb, Vb, mask, ctx, attn_out);

    proj_scalar<false><<<ggrid, 256, 0, stream>>>(ctx, Wo, bo, out, 0);
}

// Round 10
// 1394.770 us; speedup vs baseline: 1.9159x; 1.9159x over previous
//
#include <hip/hip_runtime.h>
#include <hip/hip_bf16.h>
#include <stdint.h>

// Problem constants: B=4, S=1024, E=1024, H=16, D=64
// Dtypes (r0-r9 proven): ALL inputs fp32 (mask int32), outputs fp32.
#define BATCH 4
#define SEQ   1024
#define EMB   1024
#define NH    16
#define HD    64

typedef short s8v __attribute__((ext_vector_type(8)));   // 8 bf16 (A/B frag)
typedef float f4v __attribute__((ext_vector_type(4)));   // 4 fp32 (C/D frag)

__device__ __forceinline__ float bf2f(uint32_t u16) {
    union { uint32_t u; float f; } c; c.u = u16 << 16; return c.f;
}
__device__ __forceinline__ float2 bfx2(uint32_t u) {
    union { uint32_t u; float f; } lo, hi;
    lo.u = u << 16; hi.u = u & 0xffff0000u;
    return make_float2(lo.f, hi.f);
}
__device__ __forceinline__ uint16_t f2bf(float f) {
    __hip_bfloat16 h = __float2bfloat16(f);
    return *reinterpret_cast<uint16_t*>(&h);
}
__device__ __forceinline__ short bfraw(float f) {
    __hip_bfloat16 h = __float2bfloat16(f);
    return *reinterpret_cast<short*>(&h);
}
// Load 8 consecutive fp32, pack to 8-wide bf16 fragment.
__device__ __forceinline__ s8v cvt8(const float* p) {
    float4 a = *(const float4*)p;
    float4 b = *(const float4*)(p + 4);
    s8v r;
    r[0] = bfraw(a.x); r[1] = bfraw(a.y); r[2] = bfraw(a.z); r[3] = bfraw(a.w);
    r[4] = bfraw(b.x); r[5] = bfraw(b.y); r[6] = bfraw(b.z); r[7] = bfraw(b.w);
    return r;
}

// C[M=4096,N=1024] = X @ W^T + bias, MFMA 16x16x32 bf16 (r3-exonerated).
// XF32: X fp32 (q/k/v); else X bf16 (ctx). W/bias fp32.
// scatter==1: bf16 store to [B,H,S,D] ws. scatter==0: fp32 row-major [M][N].
template<bool XF32>
__global__ __launch_bounds__(256) void proj_gemm(
        const void* __restrict__ Xv, const float* __restrict__ W,
        const float* __restrict__ bias, void* __restrict__ outv, int scatter)
{
    const int lane = threadIdx.x & 63;
    const int wave = threadIdx.x >> 6;
    const int m0 = blockIdx.y * 64 + wave * 16;
    const int n0 = blockIdx.x * 64;
    const int ar = lane & 15;     // fragment row
    const int aq = lane >> 4;     // quad -> k offset aq*8

    const float*    Xpf = (const float*)Xv    + (size_t)(m0 + ar) * EMB + aq * 8;
    const uint16_t* Xpb = (const uint16_t*)Xv + (size_t)(m0 + ar) * EMB + aq * 8;
    const float*    Wp  = W + (size_t)(n0 + ar) * EMB + aq * 8;

    f4v acc0 = {0.f,0.f,0.f,0.f}, acc1 = acc0, acc2 = acc0, acc3 = acc0;

    #pragma unroll 2
    for (int k0 = 0; k0 < EMB; k0 += 32) {
        s8v a;
        if (XF32) a = cvt8(Xpf + k0);
        else      a = *(const s8v*)(Xpb + k0);
        s8v b0 = cvt8(Wp + k0);
        s8v b1 = cvt8(Wp + 16 * EMB + k0);
        s8v b2 = cvt8(Wp + 32 * EMB + k0);
        s8v b3 = cvt8(Wp + 48 * EMB + k0);
        acc0 = __builtin_amdgcn_mfma_f32_16x16x32_bf16(a, b0, acc0, 0, 0, 0);
        acc1 = __builtin_amdgcn_mfma_f32_16x16x32_bf16(a, b1, acc1, 0, 0, 0);
        acc2 = __builtin_amdgcn_mfma_f32_16x16x32_bf16(a, b2, acc2, 0, 0, 0);
        acc3 = __builtin_amdgcn_mfma_f32_16x16x32_bf16(a, b3, acc3, 0, 0, 0);
    }

    // C/D layout: col = lane&15 (n), row = (lane>>4)*4 + r (m)  [m89]
    const int crow = m0 + aq * 4;
    f4v accs[4] = {acc0, acc1, acc2, acc3};
    #pragma unroll
    for (int nt = 0; nt < 4; ++nt) {
        const int n = n0 + nt * 16 + ar;
        const float bv = bias[n];
        #pragma unroll
        for (int r = 0; r < 4; ++r) {
            const int m = crow + r;
            const float v = accs[nt][r] + bv;
            if (scatter) {
                size_t idx = (size_t)(((m >> 10) * NH + (n >> 6)) * SEQ + (m & 1023)) * HD + (n & 63);
                ((uint16_t*)outv)[idx] = f2bf(v);
            } else {
                ((float*)outv)[(size_t)m * EMB + n] = v;
            }
        }
    }
}

// Vectorized attention (r1/r3 structure, exonerated by r3==r4==r5 bit-identity).
// block = (qt, b), 512 threads, loops over 16 heads (attn_avg in regs).
// Thread map: q = t>>5 (0..15), g = t&31.
//   QK: thread owns k = g + 32*j (j=0..31) -> s[32] in regs
//   PV: d-group = (g&7)*8, k-quarter = g>>3
__global__ __launch_bounds__(512) void attn_clever(
        const uint16_t* __restrict__ Qb, const uint16_t* __restrict__ Kb,
        const uint16_t* __restrict__ Vb, const int* __restrict__ mask,
        uint16_t* __restrict__ ctx, float* __restrict__ attn_out)
{
    __shared__ float4   Qs4[16][16];     // fp32 Q tile
    __shared__ uint4    Ks4[64][9];      // bf16 K chunk (+pad)
    __shared__ uint4    Vs4[64][9];      // bf16 V chunk
    __shared__ uint16_t P[16][1040];     // bf16 probs

    const int qt = blockIdx.x;
    const int b  = blockIdx.y;
    const int t  = threadIdx.x;
    const int q  = t >> 5;
    const int g  = t & 31;
    const int row = qt * 16 + q;

    const int* mrow = mask + ((size_t)b * SEQ + row) * SEQ;
    uint32_t mbits = 0;
    #pragma unroll
    for (int j = 0; j < 32; ++j)
        mbits |= (mrow[g + 32 * j] != 0) ? (1u << j) : 0u;

    float attn_acc[32];
    #pragma unroll
    for (int j = 0; j < 32; ++j) attn_acc[j] = 0.f;

    const int sr = t >> 3;               // staging row 0..63
    const int sc = t & 7;                // staging col (uint4)
    const int d0c = g & 7;               // PV: uint4 column
    const int kq16 = (g >> 3) * 16;      // PV: k-quarter base

    for (int h = 0; h < NH; ++h) {
        const size_t head_base = ((size_t)(b * NH + h)) * SEQ * HD;

        if (t < 256) {
            const int r = t >> 4, c4 = t & 15;
            uint2 u2 = *(const uint2*)(Qb + head_base + (size_t)(qt * 16 + r) * HD + c4 * 4);
            float2 f0 = bfx2(u2.x), f1 = bfx2(u2.y);
            float4 f; f.x = f0.x; f.y = f0.y; f.z = f1.x; f.w = f1.y;
            Qs4[r][c4] = f;
        }
        __syncthreads();

        // ---- phase A: scores ----
        float s[32];
        for (int kt = 0; kt < 16; ++kt) {
            Ks4[sr][sc] = *(const uint4*)(Kb + head_base + (size_t)(kt * 64 + sr) * HD + sc * 8);
            __syncthreads();
            #pragma unroll
            for (int jj = 0; jj < 2; ++jj) {
                const int kl = g + 32 * jj;
                float acc = 0.f;
                #pragma unroll
                for (int d8 = 0; d8 < 8; ++d8) {
                    uint4 kv = Ks4[kl][d8];
                    float4 qa = Qs4[q][2 * d8];
                    float4 qb4 = Qs4[q][2 * d8 + 1];
                    float2 k01 = bfx2(kv.x), k23 = bfx2(kv.y);
                    float2 k45 = bfx2(kv.z), k67 = bfx2(kv.w);
                    acc += qa.x * k01.x + qa.y * k01.y + qa.z * k23.x + qa.w * k23.y;
                    acc += qb4.x * k45.x + qb4.y * k45.y + qb4.z * k67.x + qb4.w * k67.y;
                }
                s[2 * kt + jj] = acc;   // s[j] <-> k = 32*j + g
            }
            __syncthreads();
        }

        // ---- mask + softmax (32 lanes sharing q) ----
        float mx = -3.0e38f;
        #pragma unroll
        for (int j = 0; j < 32; ++j) {
            s[j] = ((mbits >> j) & 1u) ? s[j] * 0.125f : -1.0e9f;
            mx = fmaxf(mx, s[j]);
        }
        #pragma unroll
        for (int off = 1; off < 32; off <<= 1) mx = fmaxf(mx, __shfl_xor(mx, off));
        float l = 0.f;
        #pragma unroll
        for (int j = 0; j < 32; ++j) { s[j] = __expf(s[j] - mx); l += s[j]; }
        #pragma unroll
        for (int off = 1; off < 32; off <<= 1) l += __shfl_xor(l, off);
        const float inv = 1.0f / l;
        #pragma unroll
        for (int j = 0; j < 32; ++j) {
            const float p = s[j] * inv;
            attn_acc[j] += p * 0.0625f;          // mean over 16 heads
            P[q][g + 32 * j] = f2bf(p);
        }

        // ---- phase B: ctx = P @ V ----
        float cacc[8];
        #pragma unroll
        for (int i = 0; i < 8; ++i) cacc[i] = 0.f;

        for (int kt = 0; kt < 16; ++kt) {
            Vs4[sr][sc] = *(const uint4*)(Vb + head_base + (size_t)(kt * 64 + sr) * HD + sc * 8);
            __syncthreads();
            const int kbase = kt * 64;
            #pragma unroll
            for (int ki = 0; ki < 16; ++ki) {
                const int kl = kq16 + ki;
                const float p = bf2f(P[q][kbase + kl]);
                uint4 vv = Vs4[kl][d0c];
                float2 v01 = bfx2(vv.x), v23 = bfx2(vv.y);
                float2 v45 = bfx2(vv.z), v67 = bfx2(vv.w);
                cacc[0] += p * v01.x; cacc[1] += p * v01.y;
                cacc[2] += p * v23.x; cacc[3] += p * v23.y;
                cacc[4] += p * v45.x; cacc[5] += p * v45.y;
                cacc[6] += p * v67.x; cacc[7] += p * v67.y;
            }
            __syncthreads();
        }
        #pragma unroll
        for (int i = 0; i < 8; ++i) {
            cacc[i] += __shfl_xor(cacc[i], 8);
            cacc[i] += __shfl_xor(cacc[i], 16);
        }
        if ((g >> 3) == 0) {
            uint16_t* cp = ctx + ((size_t)(b * SEQ + row) * NH + h) * HD + d0c * 8;
            uint32_t w[4];
            #pragma unroll
            for (int i = 0; i < 4; ++i)
                w[i] = (uint32_t)f2bf(cacc[2 * i]) | ((uint32_t)f2bf(cacc[2 * i + 1]) << 16);
            *(uint4*)cp = make_uint4(w[0], w[1], w[2], w[3]);
        }
        __syncthreads();
    }

    // ---- attn_avg out (fp32) ----
    float* ap = attn_out + ((size_t)b * SEQ + row) * SEQ;
    #pragma unroll
    for (int j = 0; j < 32; ++j) ap[g + 32 * j] = attn_acc[j];
}

extern "C" void kernel_launch(void* const* d_in, const int* in_sizes, int n_in,
                              void* d_out, int out_size, void* d_ws, size_t ws_size,
                              hipStream_t stream) {
    const float* q_in = (const float*)d_in[0];
    const float* k_in = (const float*)d_in[1];
    const float* v_in = (const float*)d_in[2];
    const int*   mask = (const int*)d_in[3];
    const float* Wq = (const float*)d_in[4];
    const float* bq = (const float*)d_in[5];
    const float* Wk = (const float*)d_in[6];
    const float* bk = (const float*)d_in[7];
    const float* Wv = (const float*)d_in[8];
    const float* bv = (const float*)d_in[9];
    const float* Wo = (const float*)d_in[10];
    const float* bo = (const float*)d_in[11];

    float* out      = (float*)d_out;                         // [B,S,E] fp32
    float* attn_out = out + (size_t)BATCH * SEQ * EMB;       // [B,S,S] fp32

    const size_t qkv_elems = (size_t)BATCH * NH * SEQ * HD;  // 4 Mi
    uint16_t* Qb  = (uint16_t*)d_ws;
    uint16_t* Kb  = Qb + qkv_elems;
    uint16_t* Vb  = Kb + qkv_elems;
    uint16_t* ctx = Vb + qkv_elems;                          // [B,S,E] bf16

    dim3 ggrid(EMB / 64, (BATCH * SEQ) / 64);                // 16 x 64
    proj_gemm<true><<<ggrid, 256, 0, stream>>>(q_in, Wq, bq, Qb, 1);
    proj_gemm<true><<<ggrid, 256, 0, stream>>>(k_in, Wk, bk, Kb, 1);
    proj_gemm<true><<<ggrid, 256, 0, stream>>>(v_in, Wv, bv, Vb, 1);

    attn_clever<<<dim3(SEQ / 16, BATCH), 512, 0, stream>>>(Qb, Kb, Vb, mask, ctx, attn_out);

    proj_gemm<false><<<ggrid, 256, 0, stream>>>(ctx, Wo, bo, out, 0);
}